// Round 9
// baseline (545.721 us; speedup 1.0000x reference)
//
#include <hip/hip_runtime.h>
#include <hip/hip_cooperative_groups.h>
#include <hip/hip_bf16.h>
#include <stdint.h>

#define N_PTS 16384
#define C_CH  64
#define D_REF 5
#define LOG2E 1.44269504088896340736f
#define JS 8
#define IBLOCKS 128       // 128 i-blocks x 128 i (4 waves x 2 i-tiles)
#define UNITS 64          // 32-j units per block (2048 j)
#define CUNITS 8
#define NCH (UNITS / CUNITS)

typedef __attribute__((ext_vector_type(8))) short bf16x8;
typedef __attribute__((ext_vector_type(4))) float f32x4;

namespace cg = cooperative_groups;

__device__ __forceinline__ unsigned short bf16rn(float v) {
    unsigned u = __builtin_bit_cast(unsigned, v) + 0x8000u;   // round-half-up
    return (unsigned short)(u >> 16);
}
__device__ __forceinline__ float bf16tof(unsigned x) {
    return __builtin_bit_cast(float, x << 16);
}
__device__ __forceinline__ unsigned pack2bf16(float lo, float hi) {
    unsigned a = __builtin_bit_cast(unsigned, lo) + 0x8000u;
    unsigned b = __builtin_bit_cast(unsigned, hi) + 0x8000u;
    return __builtin_amdgcn_perm(b, a, 0x07060302u);
}
__device__ __forceinline__ unsigned cvt2(float lo, float hi) {
#if __has_builtin(__builtin_amdgcn_cvt_pk_bf16_f32)
    typedef __attribute__((ext_vector_type(2))) __bf16 bf162_t;
    bf162_t r = __builtin_amdgcn_cvt_pk_bf16_f32(lo, hi);
    return __builtin_bit_cast(unsigned, r);
#else
    return pack2bf16(lo, hi);
#endif
}
__device__ __forceinline__ float fast_exp2(float x) {
#if __has_builtin(__builtin_amdgcn_exp2f)
    return __builtin_amdgcn_exp2f(x);
#else
    return exp2f(x);
#endif
}
__device__ __forceinline__ void dma16(const unsigned short* g, unsigned short* l) {
#if __has_builtin(__builtin_amdgcn_global_load_lds)
    __builtin_amdgcn_global_load_lds(
        (const __attribute__((address_space(1))) unsigned int*)g,
        (__attribute__((address_space(3))) unsigned int*)l, 16, 0, 0);
#else
    const int lane = threadIdx.x & 63;
    *(uint4*)(l + lane * 8) = *(const uint4*)(g);
#endif
}

// ---------------------------------------------------------------------------
// phase 1: prep (verified R5-R8 math, absmax 0.5).
//   G = log2e*(ri.rj) + hi + hj via hi/lo bf16 splits; PV-DIRECT PERMUTATION
//   bakes j-order into packA rows so G-pair output regs ARE the PV B-frag.
// blocks [0,256): U-pack (LDS transpose); [256,768): ref-pack; rest idle.
__device__ __forceinline__ void phase_prep(
    int bid, int t, const float* U, const float* ref,
    unsigned short* packA, unsigned short* packB, unsigned short* utPack,
    unsigned short* sh)
{
    if (bid < 256) {
        const int j0 = bid * 64;
        const int c  = t & 63;
        const int jb = t >> 6;
#pragma unroll
        for (int k = 0; k < 16; ++k) {
            const int jr = jb + k * 4;
            sh[c * 80 + jr] = bf16rn(U[(size_t)(j0 + jr) * C_CH + c]);  // coalesced by c
        }
        __syncthreads();
#pragma unroll
        for (int rep = 0; rep < 2; ++rep) {
            const int id   = rep * 256 + t;
            const int lane = id & 63;
            const int ct   = (id >> 6) & 3;
            const int kt   = id >> 8;
            const int m    = lane & 15;
            const int q    = lane >> 4;
            const uint4 frag = *(const uint4*)&sh[(ct * 16 + m) * 80 + kt * 32 + q * 8];
            const int jtile  = bid * 2 + kt;
            *(uint4*)&utPack[(((size_t)jtile * 4 + ct) * 64 + lane) * 8] = frag;
        }
    } else if (bid < 768) {
        const int gid  = (bid - 256) * 256 + t;        // 131072 total
        const int half = gid >> 16;                    // 0 = A(j), 1 = B(i)
        const int id   = gid & 0xFFFF;
        const int tile16 = id >> 6;
        const int lane = id & 63;
        const int q    = lane >> 4;
        const int m    = lane & 15;
        const int p = half ? (tile16 * 16 + m)
                           : ((tile16 >> 1) * 32 + (m >> 2) * 8 + (m & 3) + (tile16 & 1) * 4);

        const float* r = ref + (size_t)p * D_REF;
        float rv[5];
        float sq = 0.f;
#pragma unroll
        for (int d = 0; d < 5; ++d) { rv[d] = r[d]; sq += rv[d] * rv[d]; }
        const float h = -0.5f * LOG2E * sq;

        unsigned short bh[5], bl[5];
#pragma unroll
        for (int d = 0; d < 5; ++d) {
            const float base = half ? rv[d] * LOG2E : rv[d];
            bh[d] = bf16rn(base);
            bl[d] = bf16rn(base - bf16tof(bh[d]));
        }
        const unsigned short hh  = bf16rn(h);
        const unsigned short hl  = bf16rn(h - bf16tof(hh));
        const unsigned short one = 0x3F80;

        unsigned short outv[8];
#pragma unroll
        for (int tt = 0; tt < 8; ++tt) {
            const int k = q * 8 + tt;
            unsigned short v = 0;
            if (!half) {
                if      (k < 5)   v = bh[k];
                else if (k < 10)  v = bh[k - 5];
                else if (k < 15)  v = bl[k - 10];
                else if (k == 15) v = hh;
                else if (k == 16) v = hl;
                else if (k <= 18) v = one;
            } else {
                if      (k < 5)   v = bh[k];
                else if (k < 10)  v = bl[k - 5];
                else if (k < 15)  v = bh[k - 10];
                else if (k <= 16) v = one;
                else if (k == 17) v = hh;
                else if (k == 18) v = hl;
            }
            outv[tt] = v;
        }
        unsigned short* dst = (half ? packB : packA) + ((size_t)tile16 * 64 + lane) * 8;
        *(uint4*)dst = *(uint4*)outv;
    }
}

// ---------------------------------------------------------------------------
// phase 2: main. s=2 i-tiles/wave (acc 32 AGPR -> 4 blocks/CU), pipelined
// with one-unit skew: PV(unit u-1) issued alongside G(unit u). uf LDS-staged
// 32 KB/8-unit chunks; ga direct-global with next-unit prefetch.
__device__ __forceinline__ void phase_main(
    int bid, int t, const float* U,
    const unsigned short* packA, const unsigned short* packB,
    const unsigned short* utPack, unsigned short* part, float* out,
    unsigned short* sh, int use_part)
{
    const int lane = t & 63;
    const int wave = t >> 6;
    const int q    = lane >> 4;
    const int m    = lane & 15;
    const int ib   = bid >> 3;        // 0..127
    const int js   = bid & 7;         // bid%8 -> XCD-aligned js slices

    bf16x8 bfrag[2];
#pragma unroll
    for (int s = 0; s < 2; ++s) {
        const int itile = ib * 8 + wave * 2 + s;
        bfrag[s] = *(const bf16x8*)(packB + ((size_t)itile * 64 + lane) * 8);
    }

    f32x4 acc[2][4];
#pragma unroll
    for (int s = 0; s < 2; ++s)
#pragma unroll
        for (int ct = 0; ct < 4; ++ct) acc[s][ct] = (f32x4){0.f, 0.f, 0.f, 0.f};

    const bf16x8 zero8 = {0, 0, 0, 0, 0, 0, 0, 0};
    bf16x8 cs0 = zero8, cs1 = zero8;
    bf16x8 uf[4] = {zero8, zero8, zero8, zero8};

    const unsigned short* pA = packA + (size_t)js * UNITS * 1024 + lane * 8;
    bf16x8 ga0 = *(const bf16x8*)pA;
    bf16x8 ga1 = *(const bf16x8*)(pA + 512);

    for (int ch = 0; ch < NCH; ++ch) {
        const unsigned short* srcU = utPack + (size_t)(js * UNITS + ch * CUNITS) * 2048;
        __syncthreads();               // prior chunk's uf reads done
#pragma unroll
        for (int r = 0; r < CUNITS; ++r)
            dma16(srcU + (r * 4 + wave) * 512 + lane * 8, sh + (r * 4 + wave) * 512);
        __syncthreads();               // drains vmcnt -> LDS valid

#pragma unroll
        for (int u8 = 0; u8 < CUNITS; ++u8) {
            const f32x4 z = (f32x4){0.f, 0.f, 0.f, 0.f};
            // G (current unit) -- heads the longest chain
            f32x4 g0a = __builtin_amdgcn_mfma_f32_16x16x32_bf16(ga0, bfrag[0], z, 0, 0, 0);
            f32x4 g1a = __builtin_amdgcn_mfma_f32_16x16x32_bf16(ga1, bfrag[0], z, 0, 0, 0);
            f32x4 g0b = __builtin_amdgcn_mfma_f32_16x16x32_bf16(ga0, bfrag[1], z, 0, 0, 0);
            f32x4 g1b = __builtin_amdgcn_mfma_f32_16x16x32_bf16(ga1, bfrag[1], z, 0, 0, 0);
            // PV (previous unit) -- independent, fills the matrix pipe
#pragma unroll
            for (int ct = 0; ct < 4; ++ct) {
                acc[0][ct] = __builtin_amdgcn_mfma_f32_16x16x32_bf16(uf[ct], cs0, acc[0][ct], 0, 0, 0);
                acc[1][ct] = __builtin_amdgcn_mfma_f32_16x16x32_bf16(uf[ct], cs1, acc[1][ct], 0, 0, 0);
            }
#pragma unroll
            for (int ct = 0; ct < 4; ++ct)     // uf (current unit)
                uf[ct] = *(const bf16x8*)(sh + u8 * 2048 + ct * 512 + lane * 8);
            // ga prefetch (next unit; past-end read stays inside ws)
            const bf16x8 nga0 = *(const bf16x8*)(pA + 1024);
            const bf16x8 nga1 = *(const bf16x8*)(pA + 1536);
            pA += 1024;
            {
                union { unsigned u[4]; bf16x8 v; } sa, sb;
                sa.u[0] = cvt2(fast_exp2(g0a[0]), fast_exp2(g0a[1]));
                sa.u[1] = cvt2(fast_exp2(g0a[2]), fast_exp2(g0a[3]));
                sa.u[2] = cvt2(fast_exp2(g1a[0]), fast_exp2(g1a[1]));
                sa.u[3] = cvt2(fast_exp2(g1a[2]), fast_exp2(g1a[3]));
                sb.u[0] = cvt2(fast_exp2(g0b[0]), fast_exp2(g0b[1]));
                sb.u[1] = cvt2(fast_exp2(g0b[2]), fast_exp2(g0b[3]));
                sb.u[2] = cvt2(fast_exp2(g1b[0]), fast_exp2(g1b[1]));
                sb.u[3] = cvt2(fast_exp2(g1b[2]), fast_exp2(g1b[3]));
                cs0 = sa.v;
                cs1 = sb.v;
            }
            ga0 = nga0;
            ga1 = nga1;
        }
    }
    // drain: PV of last unit
#pragma unroll
    for (int ct = 0; ct < 4; ++ct) {
        acc[0][ct] = __builtin_amdgcn_mfma_f32_16x16x32_bf16(uf[ct], cs0, acc[0][ct], 0, 0, 0);
        acc[1][ct] = __builtin_amdgcn_mfma_f32_16x16x32_bf16(uf[ct], cs1, acc[1][ct], 0, 0, 0);
    }

    if (use_part) {
        // bf16 partials, lane-linear uint4 (16 B/lane, no write-amp)
        unsigned short* dst = part + ((size_t)js * IBLOCKS + ib) * 8192;
#pragma unroll
        for (int s = 0; s < 2; ++s)
#pragma unroll
            for (int cp = 0; cp < 2; ++cp) {
                uint4 w;
                w.x = cvt2(acc[s][cp*2+0][0], acc[s][cp*2+0][1]);
                w.y = cvt2(acc[s][cp*2+0][2], acc[s][cp*2+0][3]);
                w.z = cvt2(acc[s][cp*2+1][0], acc[s][cp*2+1][1]);
                w.w = cvt2(acc[s][cp*2+1][2], acc[s][cp*2+1][3]);
                *(uint4*)(dst + ((s * 2 + cp) * 256 + t) * 8) = w;
            }
    } else {
#pragma unroll
        for (int s = 0; s < 2; ++s) {
            const int i_glob = ib * 128 + (wave * 2 + s) * 16 + m;
#pragma unroll
            for (int ct = 0; ct < 4; ++ct)
#pragma unroll
                for (int r2 = 0; r2 < 4; ++r2) {
                    const int c = ct * 16 + q * 4 + r2;
                    float val = acc[s][ct][r2];
                    if (js == 0) val -= U[(size_t)i_glob * C_CH + c];
                    atomicAdd(&out[(size_t)i_glob * C_CH + c], val);
                }
        }
    }
}

// ---------------------------------------------------------------------------
// phase 3: reduce (blocks [0,512)). Mirror-layout linear uint4 reads, sum js,
// decode to natural (i,c), subtract U, coalesced f32x4 writes.
__device__ __forceinline__ void phase_reduce(
    int bid, int t, const unsigned short* part, const float* U, float* out)
{
    const int ib  = bid >> 2;          // 0..127
    const int row = bid & 3;
    const int s   = row >> 1;
    const int cp  = row & 1;

    float v[8];
#pragma unroll
    for (int k = 0; k < 8; ++k) v[k] = 0.f;
#pragma unroll
    for (int js = 0; js < JS; ++js) {
        const uint4 w = *(const uint4*)(part + ((size_t)js * IBLOCKS + ib) * 8192
                                        + (row * 256 + t) * 8);
        v[0] += bf16tof(w.x & 0xFFFFu); v[1] += bf16tof(w.x >> 16);
        v[2] += bf16tof(w.y & 0xFFFFu); v[3] += bf16tof(w.y >> 16);
        v[4] += bf16tof(w.z & 0xFFFFu); v[5] += bf16tof(w.z >> 16);
        v[6] += bf16tof(w.w & 0xFFFFu); v[7] += bf16tof(w.w >> 16);
    }
    const int lane = t & 63, wave = t >> 6, q = lane >> 4, m = lane & 15;
    const int i_glob = ib * 128 + (wave * 2 + s) * 16 + m;
#pragma unroll
    for (int h = 0; h < 2; ++h) {
        const int ct = cp * 2 + h;
        const size_t o = (size_t)i_glob * C_CH + ct * 16 + q * 4;
        const f32x4 uv = *(const f32x4*)(U + o);
        *(f32x4*)(out + o) = (f32x4){v[h*4+0] - uv[0], v[h*4+1] - uv[1],
                                     v[h*4+2] - uv[2], v[h*4+3] - uv[3]};
    }
}

// ---------------------------------------------------------------------------
__global__ __launch_bounds__(256, 4) void lsh_fused(
    const float* __restrict__ U, const float* __restrict__ ref,
    unsigned short* __restrict__ packA, unsigned short* __restrict__ packB,
    unsigned short* __restrict__ utPack, unsigned short* __restrict__ part,
    float* __restrict__ out)
{
    __shared__ __align__(16) unsigned short sh[16384];   // 32 KB (prep aliases)
    const int bid = blockIdx.x, t = threadIdx.x;
    cg::grid_group grid = cg::this_grid();

    phase_prep(bid, t, U, ref, packA, packB, utPack, sh);
    __threadfence();
    grid.sync();
    phase_main(bid, t, U, packA, packB, utPack, part, out, sh, 1);
    __threadfence();
    grid.sync();
    if (bid < 512) phase_reduce(bid, t, part, U, out);
}

// ------- standalone fallbacks (used only if cooperative launch fails) ------
__global__ __launch_bounds__(256) void k_prep(
    const float* __restrict__ U, const float* __restrict__ ref,
    unsigned short* __restrict__ packA, unsigned short* __restrict__ packB,
    unsigned short* __restrict__ utPack)
{
    __shared__ __align__(16) unsigned short sh[5120];
    phase_prep(blockIdx.x, threadIdx.x, U, ref, packA, packB, utPack, sh);
}
__global__ __launch_bounds__(256, 4) void k_main(
    const float* __restrict__ U,
    const unsigned short* __restrict__ packA,
    const unsigned short* __restrict__ packB,
    const unsigned short* __restrict__ utPack,
    unsigned short* __restrict__ part, float* __restrict__ out, int use_part)
{
    __shared__ __align__(16) unsigned short sh[16384];
    phase_main(blockIdx.x, threadIdx.x, U, packA, packB, utPack, part, out, sh, use_part);
}
__global__ __launch_bounds__(256) void k_reduce(
    const unsigned short* __restrict__ part, const float* __restrict__ U,
    float* __restrict__ out)
{
    phase_reduce(blockIdx.x, threadIdx.x, part, U, out);
}

extern "C" void kernel_launch(void* const* d_in, const int* in_sizes, int n_in,
                              void* d_out, int out_size, void* d_ws, size_t ws_size,
                              hipStream_t stream) {
    const float* U   = (const float*)d_in[0];
    const float* ref = (const float*)d_in[1];
    float* out = (float*)d_out;

    // ws: utPack 2 MB | packA 1 MB | packB 1 MB | bf16 partials 16 MB (JS=8)
    unsigned short* utPack = (unsigned short*)d_ws;
    unsigned short* packA  = (unsigned short*)((char*)d_ws + (size_t)2 * 1024 * 1024);
    unsigned short* packB  = (unsigned short*)((char*)d_ws + (size_t)3 * 1024 * 1024);
    unsigned short* part   = (unsigned short*)((char*)d_ws + (size_t)4 * 1024 * 1024);

    const size_t MB = 1024 * 1024;
    if (ws_size >= 20 * MB) {
        void* args[] = {(void*)&U, (void*)&ref, (void*)&packA, (void*)&packB,
                        (void*)&utPack, (void*)&part, (void*)&out};
        hipError_t e = hipLaunchCooperativeKernel((const void*)lsh_fused,
                                                  dim3(IBLOCKS * JS), dim3(256),
                                                  args, 0, stream);
        if (e != hipSuccess) {
            k_prep<<<768, 256, 0, stream>>>(U, ref, packA, packB, utPack);
            k_main<<<IBLOCKS * JS, 256, 0, stream>>>(U, packA, packB, utPack,
                                                     part, out, 1);
            k_reduce<<<512, 256, 0, stream>>>(part, U, out);
        }
    } else {
        hipMemsetAsync(d_out, 0, (size_t)out_size * sizeof(float), stream);
        k_prep<<<768, 256, 0, stream>>>(U, ref, packA, packB, utPack);
        k_main<<<IBLOCKS * JS, 256, 0, stream>>>(U, packA, packB, utPack,
                                                 part, out, 0);
    }
}

// Round 10
// 225.488 us; speedup vs baseline: 2.4202x; 2.4202x over previous
//
#include <hip/hip_runtime.h>
#include <hip/hip_bf16.h>
#include <stdint.h>

#define N_PTS 16384
#define C_CH  64
#define D_REF 5
#define LOG2E 1.44269504088896340736f
#define IBLOCKS 64        // 256 i per block (4 waves x 4 i-tiles x 16)

typedef __attribute__((ext_vector_type(8))) short bf16x8;
typedef __attribute__((ext_vector_type(4))) float f32x4;

__device__ __forceinline__ unsigned short bf16rn(float v) {
    unsigned u = __builtin_bit_cast(unsigned, v) + 0x8000u;   // round-half-up
    return (unsigned short)(u >> 16);
}
__device__ __forceinline__ float bf16tof(unsigned x) {
    return __builtin_bit_cast(float, x << 16);
}
__device__ __forceinline__ unsigned pack2bf16(float lo, float hi) {
    unsigned a = __builtin_bit_cast(unsigned, lo) + 0x8000u;
    unsigned b = __builtin_bit_cast(unsigned, hi) + 0x8000u;
    return __builtin_amdgcn_perm(b, a, 0x07060302u);
}
__device__ __forceinline__ unsigned cvt2(float lo, float hi) {
#if __has_builtin(__builtin_amdgcn_cvt_pk_bf16_f32)
    typedef __attribute__((ext_vector_type(2))) __bf16 bf162_t;
    bf162_t r = __builtin_amdgcn_cvt_pk_bf16_f32(lo, hi);
    return __builtin_bit_cast(unsigned, r);
#else
    return pack2bf16(lo, hi);
#endif
}
__device__ __forceinline__ float fast_exp2(float x) {
#if __has_builtin(__builtin_amdgcn_exp2f)
    return __builtin_amdgcn_exp2f(x);
#else
    return exp2f(x);
#endif
}
__device__ __forceinline__ void dma16(const unsigned short* g, unsigned short* l) {
#if __has_builtin(__builtin_amdgcn_global_load_lds)
    __builtin_amdgcn_global_load_lds(
        (const __attribute__((address_space(1))) unsigned int*)g,
        (__attribute__((address_space(3))) unsigned int*)l, 16, 0, 0);
#else
    const int lane = threadIdx.x & 63;
    *(uint4*)(l + lane * 8) = *(const uint4*)(g);
#endif
}

// ---------------------------------------------------------------------------
// prep (verified R5-R8 math, absmax 0.5): G = log2e*(ri.rj) + hi + hj via
// hi/lo bf16 splits; PV-DIRECT PERMUTATION bakes j-order into packA rows so
// the G-pair output regs on lane (q,m) ARE the PV B-fragment.
// Block 0 additionally zeroes the per-ib ticket counters.
__global__ __launch_bounds__(256) void prep_all(
    const float* __restrict__ U, const float* __restrict__ ref,
    unsigned short* __restrict__ packA, unsigned short* __restrict__ packB,
    unsigned short* __restrict__ utPack, int* __restrict__ cnt)
{
    __shared__ unsigned short tile[64 * 80];
    const int bid = blockIdx.x;
    const int t   = threadIdx.x;

    if (bid == 0 && t < IBLOCKS) cnt[t] = 0;   // tickets for main's last-block reduce

    if (bid < 512) {
        const int gid  = bid * 256 + t;                // 131072 total
        const int half = gid >> 16;                    // 0 = A(j), 1 = B(i)
        const int id   = gid & 0xFFFF;
        const int tile16 = id >> 6;
        const int lane = id & 63;
        const int q    = lane >> 4;
        const int m    = lane & 15;
        const int p = half ? (tile16 * 16 + m)
                           : ((tile16 >> 1) * 32 + (m >> 2) * 8 + (m & 3) + (tile16 & 1) * 4);

        const float* r = ref + (size_t)p * D_REF;
        float rv[5];
        float sq = 0.f;
#pragma unroll
        for (int d = 0; d < 5; ++d) { rv[d] = r[d]; sq += rv[d] * rv[d]; }
        const float h = -0.5f * LOG2E * sq;

        unsigned short bh[5], bl[5];
#pragma unroll
        for (int d = 0; d < 5; ++d) {
            const float base = half ? rv[d] * LOG2E : rv[d];
            bh[d] = bf16rn(base);
            bl[d] = bf16rn(base - bf16tof(bh[d]));
        }
        const unsigned short hh  = bf16rn(h);
        const unsigned short hl  = bf16rn(h - bf16tof(hh));
        const unsigned short one = 0x3F80;

        unsigned short outv[8];
#pragma unroll
        for (int tt = 0; tt < 8; ++tt) {
            const int k = q * 8 + tt;
            unsigned short v = 0;
            if (!half) {
                if      (k < 5)   v = bh[k];
                else if (k < 10)  v = bh[k - 5];
                else if (k < 15)  v = bl[k - 10];
                else if (k == 15) v = hh;
                else if (k == 16) v = hl;
                else if (k <= 18) v = one;
            } else {
                if      (k < 5)   v = bh[k];
                else if (k < 10)  v = bl[k - 5];
                else if (k < 15)  v = bh[k - 10];
                else if (k <= 16) v = one;
                else if (k == 17) v = hh;
                else if (k == 18) v = hl;
            }
            outv[tt] = v;
        }
        unsigned short* dst = (half ? packB : packA) + ((size_t)tile16 * 64 + lane) * 8;
        *(uint4*)dst = *(uint4*)outv;
    } else {
        const int b  = bid - 512;
        const int j0 = b * 64;
        const int c  = t & 63;
        const int jb = t >> 6;
#pragma unroll
        for (int k = 0; k < 16; ++k) {
            const int jr = jb + k * 4;
            tile[c * 80 + jr] = bf16rn(U[(size_t)(j0 + jr) * C_CH + c]);  // coalesced by c
        }
        __syncthreads();
#pragma unroll
        for (int rep = 0; rep < 2; ++rep) {
            const int id   = rep * 256 + t;            // 512 frag-lanes
            const int lane = id & 63;
            const int ct   = (id >> 6) & 3;
            const int kt   = id >> 8;                  // 0..1
            const int m    = lane & 15;
            const int q    = lane >> 4;
            const uint4 frag = *(const uint4*)&tile[(ct * 16 + m) * 80 + kt * 32 + q * 8];
            const int jtile  = b * 2 + kt;
            *(uint4*)&utPack[(((size_t)jtile * 4 + ct) * 64 + lane) * 8] = frag;
        }
    }
}

// ---------------------------------------------------------------------------
// main (R8 structure, proven 60.3 us): software-pipelined K-loop, PV lags one
// s-pair step; uf LDS-staged 32 KB/8-unit chunks; ga direct-global prefetch.
// NEW: last-block ticket folds the js-reduction into this kernel (2 dispatches
// total). Writers: partial stores -> __syncthreads (vmcnt drain) -> t0 fence
// (L2 wb) + atomicAdd ticket. Last block: fence (L2 inv) -> read 16 slices ->
// out = sum - U. No spinning anywhere.
template<int JS>
__global__ __launch_bounds__(256, 3) void lsh_main(
    const float* __restrict__ U,
    const unsigned short* __restrict__ packA,
    const unsigned short* __restrict__ packB,
    const unsigned short* __restrict__ utPack,
    unsigned short* __restrict__ part,
    int* __restrict__ cnt,
    float* __restrict__ out,
    int use_part)
{
    constexpr int UNITS  = (N_PTS / JS) / 32;
    constexpr int CUNITS = 8;
    constexpr int NCH    = UNITS / CUNITS;
    __shared__ __align__(16) unsigned short sh[CUNITS * 2048];   // 32 KB
    __shared__ int lastFlag;

    const int t    = threadIdx.x;
    const int lane = t & 63;
    const int wave = t >> 6;
    const int q    = lane >> 4;
    const int m    = lane & 15;

    const int ib = blockIdx.x / JS;
    const int js = blockIdx.x % JS;

    bf16x8 bfrag[4];
#pragma unroll
    for (int s = 0; s < 4; ++s) {
        const int itile = ib * 16 + wave * 4 + s;
        bfrag[s] = *(const bf16x8*)(packB + ((size_t)itile * 64 + lane) * 8);
    }

    f32x4 acc[4][4];
#pragma unroll
    for (int s = 0; s < 4; ++s)
#pragma unroll
        for (int ct = 0; ct < 4; ++ct) acc[s][ct] = (f32x4){0.f, 0.f, 0.f, 0.f};

    const bf16x8 zero8 = {0, 0, 0, 0, 0, 0, 0, 0};
    bf16x8 cs0 = zero8, cs1 = zero8;
    bf16x8 uf[4] = {zero8, zero8, zero8, zero8};

    const unsigned short* pA = packA + ((size_t)js * UNITS) * 1024 + lane * 8;
    bf16x8 ga0 = *(const bf16x8*)pA;
    bf16x8 ga1 = *(const bf16x8*)(pA + 512);

    for (int ch = 0; ch < NCH; ++ch) {
        const unsigned short* srcU = utPack + (size_t)(js * UNITS + ch * CUNITS) * 2048;
        __syncthreads();                   // prior chunk's uf reads done
#pragma unroll
        for (int r = 0; r < CUNITS; ++r)
            dma16(srcU + (r * 4 + wave) * 512 + lane * 8, sh + (r * 4 + wave) * 512);
        __syncthreads();                   // drains vmcnt -> LDS valid

#pragma unroll
        for (int u8 = 0; u8 < CUNITS; ++u8) {
            const f32x4 z = (f32x4){0.f, 0.f, 0.f, 0.f};
            // ---------- step A: G(pair0) + PV(pair1 of prev unit) ----------
            f32x4 g0a = __builtin_amdgcn_mfma_f32_16x16x32_bf16(ga0, bfrag[0], z, 0, 0, 0);
            f32x4 g1a = __builtin_amdgcn_mfma_f32_16x16x32_bf16(ga1, bfrag[0], z, 0, 0, 0);
            f32x4 g0b = __builtin_amdgcn_mfma_f32_16x16x32_bf16(ga0, bfrag[1], z, 0, 0, 0);
            f32x4 g1b = __builtin_amdgcn_mfma_f32_16x16x32_bf16(ga1, bfrag[1], z, 0, 0, 0);
#pragma unroll
            for (int ct = 0; ct < 4; ++ct) {
                acc[2][ct] = __builtin_amdgcn_mfma_f32_16x16x32_bf16(uf[ct], cs0, acc[2][ct], 0, 0, 0);
                acc[3][ct] = __builtin_amdgcn_mfma_f32_16x16x32_bf16(uf[ct], cs1, acc[3][ct], 0, 0, 0);
            }
#pragma unroll
            for (int ct = 0; ct < 4; ++ct)    // uf(current unit), used in step B
                uf[ct] = *(const bf16x8*)(sh + u8 * 2048 + ct * 512 + lane * 8);
            {
                union { unsigned u[4]; bf16x8 v; } sa, sb;
                sa.u[0] = cvt2(fast_exp2(g0a[0]), fast_exp2(g0a[1]));
                sa.u[1] = cvt2(fast_exp2(g0a[2]), fast_exp2(g0a[3]));
                sa.u[2] = cvt2(fast_exp2(g1a[0]), fast_exp2(g1a[1]));
                sa.u[3] = cvt2(fast_exp2(g1a[2]), fast_exp2(g1a[3]));
                sb.u[0] = cvt2(fast_exp2(g0b[0]), fast_exp2(g0b[1]));
                sb.u[1] = cvt2(fast_exp2(g0b[2]), fast_exp2(g0b[3]));
                sb.u[2] = cvt2(fast_exp2(g1b[0]), fast_exp2(g1b[1]));
                sb.u[3] = cvt2(fast_exp2(g1b[2]), fast_exp2(g1b[3]));
                cs0 = sa.v;
                cs1 = sb.v;
            }
            // ---------- step B: G(pair1) + PV(pair0 of current unit) -------
            f32x4 h0a = __builtin_amdgcn_mfma_f32_16x16x32_bf16(ga0, bfrag[2], z, 0, 0, 0);
            f32x4 h1a = __builtin_amdgcn_mfma_f32_16x16x32_bf16(ga1, bfrag[2], z, 0, 0, 0);
            f32x4 h0b = __builtin_amdgcn_mfma_f32_16x16x32_bf16(ga0, bfrag[3], z, 0, 0, 0);
            f32x4 h1b = __builtin_amdgcn_mfma_f32_16x16x32_bf16(ga1, bfrag[3], z, 0, 0, 0);
#pragma unroll
            for (int ct = 0; ct < 4; ++ct) {
                acc[0][ct] = __builtin_amdgcn_mfma_f32_16x16x32_bf16(uf[ct], cs0, acc[0][ct], 0, 0, 0);
                acc[1][ct] = __builtin_amdgcn_mfma_f32_16x16x32_bf16(uf[ct], cs1, acc[1][ct], 0, 0, 0);
            }
            const bf16x8 nga0 = *(const bf16x8*)(pA + 1024);
            const bf16x8 nga1 = *(const bf16x8*)(pA + 1536);
            pA += 1024;
            {
                union { unsigned u[4]; bf16x8 v; } sa, sb;
                sa.u[0] = cvt2(fast_exp2(h0a[0]), fast_exp2(h0a[1]));
                sa.u[1] = cvt2(fast_exp2(h0a[2]), fast_exp2(h0a[3]));
                sa.u[2] = cvt2(fast_exp2(h1a[0]), fast_exp2(h1a[1]));
                sa.u[3] = cvt2(fast_exp2(h1a[2]), fast_exp2(h1a[3]));
                sb.u[0] = cvt2(fast_exp2(h0b[0]), fast_exp2(h0b[1]));
                sb.u[1] = cvt2(fast_exp2(h0b[2]), fast_exp2(h0b[3]));
                sb.u[2] = cvt2(fast_exp2(h1b[0]), fast_exp2(h1b[1]));
                sb.u[3] = cvt2(fast_exp2(h1b[2]), fast_exp2(h1b[3]));
                cs0 = sa.v;
                cs1 = sb.v;
            }
            ga0 = nga0;
            ga1 = nga1;
        }
    }
    // drain: pair1 of last unit
#pragma unroll
    for (int ct = 0; ct < 4; ++ct) {
        acc[2][ct] = __builtin_amdgcn_mfma_f32_16x16x32_bf16(uf[ct], cs0, acc[2][ct], 0, 0, 0);
        acc[3][ct] = __builtin_amdgcn_mfma_f32_16x16x32_bf16(uf[ct], cs1, acc[3][ct], 0, 0, 0);
    }

    if (use_part) {
        // bf16 partials, lane-linear 16 B/lane (fully coalesced, no RMW)
        unsigned short* dst = part + ((size_t)js * IBLOCKS + ib) * 16384;
#pragma unroll
        for (int s = 0; s < 4; ++s)
#pragma unroll
            for (int cp = 0; cp < 2; ++cp) {
                uint4 w;
                w.x = cvt2(acc[s][cp*2+0][0], acc[s][cp*2+0][1]);
                w.y = cvt2(acc[s][cp*2+0][2], acc[s][cp*2+0][3]);
                w.z = cvt2(acc[s][cp*2+1][0], acc[s][cp*2+1][1]);
                w.w = cvt2(acc[s][cp*2+1][2], acc[s][cp*2+1][3]);
                *(uint4*)(dst + ((s * 2 + cp) * 256 + t) * 8) = w;
            }

        // ----- last-block ticket: fold the js-reduction into this launch ---
        __syncthreads();                    // all partial stores complete (vmcnt 0)
        if (t == 0) {
            __threadfence();                // release: L2 write-back to L3
            lastFlag = (atomicAdd(&cnt[ib], 1) == JS - 1) ? 1 : 0;
        }
        __syncthreads();
        if (lastFlag) {
            __threadfence();                // acquire: invalidate L1/L2 for fresh reads
#pragma unroll
            for (int s = 0; s < 4; ++s)
#pragma unroll
                for (int cp = 0; cp < 2; ++cp) {
                    float v[8];
#pragma unroll
                    for (int k = 0; k < 8; ++k) v[k] = 0.f;
                    const int row = s * 2 + cp;
                    for (int j2 = 0; j2 < JS; ++j2) {
                        const uint4 w = *(const uint4*)(part
                            + ((size_t)j2 * IBLOCKS + ib) * 16384
                            + (row * 256 + t) * 8);
                        v[0] += bf16tof(w.x & 0xFFFFu); v[1] += bf16tof(w.x >> 16);
                        v[2] += bf16tof(w.y & 0xFFFFu); v[3] += bf16tof(w.y >> 16);
                        v[4] += bf16tof(w.z & 0xFFFFu); v[5] += bf16tof(w.z >> 16);
                        v[6] += bf16tof(w.w & 0xFFFFu); v[7] += bf16tof(w.w >> 16);
                    }
                    const int i_glob = ib * 256 + (wave * 4 + s) * 16 + m;
#pragma unroll
                    for (int h = 0; h < 2; ++h) {
                        const size_t o = (size_t)i_glob * C_CH + (cp * 2 + h) * 16 + q * 4;
                        const f32x4 uv = *(const f32x4*)(U + o);
                        *(f32x4*)(out + o) = (f32x4){v[h*4+0] - uv[0], v[h*4+1] - uv[1],
                                                     v[h*4+2] - uv[2], v[h*4+3] - uv[3]};
                    }
                }
        }
    } else {
#pragma unroll
        for (int s = 0; s < 4; ++s) {
            const int i_glob = ib * 256 + (wave * 4 + s) * 16 + m;
#pragma unroll
            for (int ct = 0; ct < 4; ++ct)
#pragma unroll
                for (int r2 = 0; r2 < 4; ++r2) {
                    const int c = ct * 16 + q * 4 + r2;
                    float val = acc[s][ct][r2];
                    if (js == 0) val -= U[(size_t)i_glob * C_CH + c];
                    atomicAdd(&out[(size_t)i_glob * C_CH + c], val);
                }
        }
    }
}

extern "C" void kernel_launch(void* const* d_in, const int* in_sizes, int n_in,
                              void* d_out, int out_size, void* d_ws, size_t ws_size,
                              hipStream_t stream) {
    const float* U   = (const float*)d_in[0];
    const float* ref = (const float*)d_in[1];
    float* out = (float*)d_out;

    // ws: utPack 2 MB | packA 1 MB | packB 1 MB | bf16 partials 32 MB (JS=16)
    //     | tickets (64 ints) at 36 MB
    unsigned short* utPack = (unsigned short*)d_ws;
    unsigned short* packA  = (unsigned short*)((char*)d_ws + (size_t)2 * 1024 * 1024);
    unsigned short* packB  = (unsigned short*)((char*)d_ws + (size_t)3 * 1024 * 1024);
    unsigned short* part   = (unsigned short*)((char*)d_ws + (size_t)4 * 1024 * 1024);
    int*            cnt    = (int*)((char*)d_ws + (size_t)36 * 1024 * 1024);

    const size_t MB = 1024 * 1024;
    prep_all<<<768, 256, 0, stream>>>(U, ref, packA, packB, utPack, cnt);

    if (ws_size >= 37 * MB) {
        lsh_main<16><<<IBLOCKS * 16, 256, 0, stream>>>(U, packA, packB, utPack,
                                                       part, cnt, out, 1);
    } else {
        hipMemsetAsync(d_out, 0, (size_t)out_size * sizeof(float), stream);
        lsh_main<8><<<IBLOCKS * 8, 256, 0, stream>>>(U, packA, packB, utPack,
                                                     part, cnt, out, 0);
    }
}

// Round 11
// 137.127 us; speedup vs baseline: 3.9797x; 1.6444x over previous
//
#include <hip/hip_runtime.h>
#include <hip/hip_bf16.h>
#include <stdint.h>

#define N_PTS 16384
#define C_CH  64
#define D_REF 5
#define LOG2E 1.44269504088896340736f
#define IBLOCKS 64        // 256 i per block (4 waves x 4 i-tiles x 16)

typedef __attribute__((ext_vector_type(8))) short bf16x8;
typedef __attribute__((ext_vector_type(4))) float f32x4;

__device__ __forceinline__ unsigned short bf16rn(float v) {
    unsigned u = __builtin_bit_cast(unsigned, v) + 0x8000u;   // round-half-up
    return (unsigned short)(u >> 16);
}
__device__ __forceinline__ float bf16tof(unsigned x) {
    return __builtin_bit_cast(float, x << 16);
}
__device__ __forceinline__ unsigned pack2bf16(float lo, float hi) {
    unsigned a = __builtin_bit_cast(unsigned, lo) + 0x8000u;
    unsigned b = __builtin_bit_cast(unsigned, hi) + 0x8000u;
    return __builtin_amdgcn_perm(b, a, 0x07060302u);
}
__device__ __forceinline__ unsigned cvt2(float lo, float hi) {
#if __has_builtin(__builtin_amdgcn_cvt_pk_bf16_f32)
    typedef __attribute__((ext_vector_type(2))) __bf16 bf162_t;
    bf162_t r = __builtin_amdgcn_cvt_pk_bf16_f32(lo, hi);
    return __builtin_bit_cast(unsigned, r);
#else
    return pack2bf16(lo, hi);
#endif
}
__device__ __forceinline__ float fast_exp2(float x) {
#if __has_builtin(__builtin_amdgcn_exp2f)
    return __builtin_amdgcn_exp2f(x);
#else
    return exp2f(x);
#endif
}
__device__ __forceinline__ void dma16(const unsigned short* g, unsigned short* l) {
#if __has_builtin(__builtin_amdgcn_global_load_lds)
    __builtin_amdgcn_global_load_lds(
        (const __attribute__((address_space(1))) unsigned int*)g,
        (__attribute__((address_space(3))) unsigned int*)l, 16, 0, 0);
#else
    const int lane = threadIdx.x & 63;
    *(uint4*)(l + lane * 8) = *(const uint4*)(g);
#endif
}

// ---------------------------------------------------------------------------
// prep (verified R5-R8 math, absmax 0.5): G = log2e*(ri.rj) + hi + hj via
// hi/lo bf16 splits; PV-DIRECT PERMUTATION bakes j-order into packA rows so
// the G-pair output regs on lane (q,m) ARE the PV B-fragment.
__global__ __launch_bounds__(256) void prep_all(
    const float* __restrict__ U, const float* __restrict__ ref,
    unsigned short* __restrict__ packA, unsigned short* __restrict__ packB,
    unsigned short* __restrict__ utPack)
{
    __shared__ unsigned short tile[64 * 80];
    const int bid = blockIdx.x;
    const int t   = threadIdx.x;

    if (bid < 512) {
        const int gid  = bid * 256 + t;                // 131072 total
        const int half = gid >> 16;                    // 0 = A(j), 1 = B(i)
        const int id   = gid & 0xFFFF;
        const int tile16 = id >> 6;
        const int lane = id & 63;
        const int q    = lane >> 4;
        const int m    = lane & 15;
        const int p = half ? (tile16 * 16 + m)
                           : ((tile16 >> 1) * 32 + (m >> 2) * 8 + (m & 3) + (tile16 & 1) * 4);

        const float* r = ref + (size_t)p * D_REF;
        float rv[5];
        float sq = 0.f;
#pragma unroll
        for (int d = 0; d < 5; ++d) { rv[d] = r[d]; sq += rv[d] * rv[d]; }
        const float h = -0.5f * LOG2E * sq;

        unsigned short bh[5], bl[5];
#pragma unroll
        for (int d = 0; d < 5; ++d) {
            const float base = half ? rv[d] * LOG2E : rv[d];
            bh[d] = bf16rn(base);
            bl[d] = bf16rn(base - bf16tof((unsigned)bh[d]));
        }
        const unsigned short hh  = bf16rn(h);
        const unsigned short hl  = bf16rn(h - bf16tof((unsigned)hh));
        const unsigned short one = 0x3F80;

        unsigned short outv[8];
#pragma unroll
        for (int tt = 0; tt < 8; ++tt) {
            const int k = q * 8 + tt;
            unsigned short v = 0;
            if (!half) {
                if      (k < 5)   v = bh[k];
                else if (k < 10)  v = bh[k - 5];
                else if (k < 15)  v = bl[k - 10];
                else if (k == 15) v = hh;
                else if (k == 16) v = hl;
                else if (k <= 18) v = one;
            } else {
                if      (k < 5)   v = bh[k];
                else if (k < 10)  v = bl[k - 5];
                else if (k < 15)  v = bh[k - 10];
                else if (k <= 16) v = one;
                else if (k == 17) v = hh;
                else if (k == 18) v = hl;
            }
            outv[tt] = v;
        }
        unsigned short* dst = (half ? packB : packA) + ((size_t)tile16 * 64 + lane) * 8;
        *(uint4*)dst = *(uint4*)outv;
    } else {
        const int b  = bid - 512;
        const int j0 = b * 64;
        const int c  = t & 63;
        const int jb = t >> 6;
#pragma unroll
        for (int k = 0; k < 16; ++k) {
            const int jr = jb + k * 4;
            tile[c * 80 + jr] = bf16rn(U[(size_t)(j0 + jr) * C_CH + c]);  // coalesced by c
        }
        __syncthreads();
#pragma unroll
        for (int rep = 0; rep < 2; ++rep) {
            const int id   = rep * 256 + t;            // 512 frag-lanes
            const int lane = id & 63;
            const int ct   = (id >> 6) & 3;
            const int kt   = id >> 8;                  // 0..1
            const int m    = lane & 15;
            const int q    = lane >> 4;
            const uint4 frag = *(const uint4*)&tile[(ct * 16 + m) * 80 + kt * 32 + q * 8];
            const int jtile  = b * 2 + kt;
            *(uint4*)&utPack[(((size_t)jtile * 4 + ct) * 64 + lane) * 8] = frag;
        }
    }
}

// ---------------------------------------------------------------------------
// main: s=4 i-tiles/wave (acc 64 AGPR + ~60 VGPR = 124 regs -> TRUE 4
// blocks/CU with __launch_bounds__(256,4); grid = exactly 4/CU, no straggler
// tail). uf staged via DOUBLE-BUFFERED LDS (2 x 16 KB, CUNITS=4): DMA for
// chunk k+1 issued before computing chunk k -> ONE barrier per chunk whose
// vmcnt drain is nearly free (DMA had a full chunk of compute in flight).
// ga direct-global rolling prefetch. bf16 partials, lane-linear 16 B/lane.
template<int JS>
__global__ __launch_bounds__(256, 4) void lsh_main(
    const float* __restrict__ U,
    const unsigned short* __restrict__ packA,
    const unsigned short* __restrict__ packB,
    const unsigned short* __restrict__ utPack,
    unsigned short* __restrict__ part,
    float* __restrict__ out,
    int use_part)
{
    constexpr int UNITS  = (N_PTS / JS) / 32;   // 32 at JS=16
    constexpr int CUNITS = 4;
    constexpr int NCH    = UNITS / CUNITS;      // 8 at JS=16
    __shared__ __align__(16) unsigned short sh[2 * CUNITS * 2048];   // 32 KB

    const int t    = threadIdx.x;
    const int lane = t & 63;
    const int wave = t >> 6;
    const int q    = lane >> 4;
    const int m    = lane & 15;

    const int ib = blockIdx.x / JS;
    const int js = blockIdx.x % JS;

    bf16x8 bfrag[4];
#pragma unroll
    for (int s = 0; s < 4; ++s) {
        const int itile = ib * 16 + wave * 4 + s;
        bfrag[s] = *(const bf16x8*)(packB + ((size_t)itile * 64 + lane) * 8);
    }

    f32x4 acc[4][4];
#pragma unroll
    for (int s = 0; s < 4; ++s)
#pragma unroll
        for (int ct = 0; ct < 4; ++ct) acc[s][ct] = (f32x4){0.f, 0.f, 0.f, 0.f};

    const unsigned short* pA = packA + ((size_t)js * UNITS) * 1024 + lane * 8;
    bf16x8 ga0 = *(const bf16x8*)pA;
    bf16x8 ga1 = *(const bf16x8*)(pA + 512);

    const unsigned short* srcU0 = utPack + ((size_t)js * UNITS) * 2048;
    // prologue: DMA chunk 0 -> buffer 0
#pragma unroll
    for (int r = 0; r < CUNITS; ++r)
        dma16(srcU0 + (r * 4 + wave) * 512 + lane * 8, sh + (r * 4 + wave) * 512);
    __syncthreads();                       // drain DMA0

    for (int ch = 0; ch < NCH; ++ch) {
        unsigned short* buf = sh + (ch & 1) * (CUNITS * 2048);
        // issue next chunk's DMA into the other buffer (free since ch-1 barrier)
        if (ch + 1 < NCH) {
            const unsigned short* srcN = srcU0 + (size_t)(ch + 1) * (CUNITS * 2048);
            unsigned short* nbuf = sh + ((ch + 1) & 1) * (CUNITS * 2048);
#pragma unroll
            for (int r = 0; r < CUNITS; ++r)
                dma16(srcN + (r * 4 + wave) * 512 + lane * 8, nbuf + (r * 4 + wave) * 512);
        }

#pragma unroll
        for (int u4 = 0; u4 < CUNITS; ++u4) {
            // rolling ga prefetch (past-end read stays inside ws)
            const bf16x8 nga0 = *(const bf16x8*)(pA + 1024);
            const bf16x8 nga1 = *(const bf16x8*)(pA + 1536);

            const f32x4 z = (f32x4){0.f, 0.f, 0.f, 0.f};
            bf16x8 sfrag[4];
#pragma unroll
            for (int sp = 0; sp < 2; ++sp) {           // s in pairs: bound regs
                f32x4 g0a = __builtin_amdgcn_mfma_f32_16x16x32_bf16(ga0, bfrag[sp*2+0], z, 0, 0, 0);
                f32x4 g1a = __builtin_amdgcn_mfma_f32_16x16x32_bf16(ga1, bfrag[sp*2+0], z, 0, 0, 0);
                f32x4 g0b = __builtin_amdgcn_mfma_f32_16x16x32_bf16(ga0, bfrag[sp*2+1], z, 0, 0, 0);
                f32x4 g1b = __builtin_amdgcn_mfma_f32_16x16x32_bf16(ga1, bfrag[sp*2+1], z, 0, 0, 0);
                union { unsigned u[4]; bf16x8 v; } sa, sb;
                sa.u[0] = cvt2(fast_exp2(g0a[0]), fast_exp2(g0a[1]));
                sa.u[1] = cvt2(fast_exp2(g0a[2]), fast_exp2(g0a[3]));
                sa.u[2] = cvt2(fast_exp2(g1a[0]), fast_exp2(g1a[1]));
                sa.u[3] = cvt2(fast_exp2(g1a[2]), fast_exp2(g1a[3]));
                sb.u[0] = cvt2(fast_exp2(g0b[0]), fast_exp2(g0b[1]));
                sb.u[1] = cvt2(fast_exp2(g0b[2]), fast_exp2(g0b[3]));
                sb.u[2] = cvt2(fast_exp2(g1b[0]), fast_exp2(g1b[1]));
                sb.u[3] = cvt2(fast_exp2(g1b[2]), fast_exp2(g1b[3]));
                sfrag[sp*2+0] = sa.v;                  // == PV B-frag for 32 j
                sfrag[sp*2+1] = sb.v;
            }
#pragma unroll
            for (int ct = 0; ct < 4; ++ct) {
                const bf16x8 uf = *(const bf16x8*)(buf + u4 * 2048 + ct * 512 + lane * 8);
#pragma unroll
                for (int s = 0; s < 4; ++s)
                    acc[s][ct] = __builtin_amdgcn_mfma_f32_16x16x32_bf16(
                        uf, sfrag[s], acc[s][ct], 0, 0, 0);
            }
            pA += 1024;
            ga0 = nga0;
            ga1 = nga1;
        }
        __syncthreads();   // readers done with buf; next DMA (in flight a full
                           // chunk) also drains here -- nearly free
    }

    if (use_part) {
        // bf16 partials, lane-linear 16 B/lane (fully coalesced, no RMW)
        unsigned short* dst = part + ((size_t)js * IBLOCKS + ib) * 16384;
#pragma unroll
        for (int s = 0; s < 4; ++s)
#pragma unroll
            for (int cp = 0; cp < 2; ++cp) {
                uint4 w;
                w.x = cvt2(acc[s][cp*2+0][0], acc[s][cp*2+0][1]);
                w.y = cvt2(acc[s][cp*2+0][2], acc[s][cp*2+0][3]);
                w.z = cvt2(acc[s][cp*2+1][0], acc[s][cp*2+1][1]);
                w.w = cvt2(acc[s][cp*2+1][2], acc[s][cp*2+1][3]);
                *(uint4*)(dst + ((s * 2 + cp) * 256 + t) * 8) = w;
            }
    } else {
#pragma unroll
        for (int s = 0; s < 4; ++s) {
            const int i_glob = ib * 256 + (wave * 4 + s) * 16 + m;
#pragma unroll
            for (int ct = 0; ct < 4; ++ct)
#pragma unroll
                for (int r2 = 0; r2 < 4; ++r2) {
                    const int c = ct * 16 + q * 4 + r2;
                    float val = acc[s][ct][r2];
                    if (js == 0) val -= U[(size_t)i_glob * C_CH + c];
                    atomicAdd(&out[(size_t)i_glob * C_CH + c], val);
                }
        }
    }
}

// ---------------------------------------------------------------------------
// reduce: out = sum_js bf16(part[js]) - U, gather-decoding the lane-linear
// partial layout; output writes are coalesced f32x4. (verified R8)
template<int JS>
__global__ __launch_bounds__(256) void reduce_part(
    const unsigned short* __restrict__ part, const f32x4* __restrict__ Uv,
    f32x4* __restrict__ out)
{
    const int x  = blockIdx.x * 256 + threadIdx.x;     // [0, 2^18) f32x4 units
    const int i  = x >> 4;
    const int c4 = (x & 15) * 4;                        // c = c4 .. c4+3
    const int blk = i >> 8, il = i & 255;
    const int wv = il >> 6, s = (il >> 4) & 3, mm = il & 15;
    const int ct = c4 >> 4, qq = (c4 >> 2) & 3;
    const int cp = ct >> 1, cti = ct & 1;
    const size_t off = (size_t)blk * 16384 +
        (size_t)(((s * 2 + cp) * 256) + (wv * 64 + qq * 16 + mm)) * 8 + cti * 4;
    float s0 = 0.f, s1 = 0.f, s2 = 0.f, s3 = 0.f;
#pragma unroll
    for (int js = 0; js < JS; ++js) {
        const uint2 w = *(const uint2*)(part + (size_t)js * (IBLOCKS * 16384) + off);
        s0 += bf16tof(w.x & 0xFFFFu);
        s1 += bf16tof(w.x >> 16);
        s2 += bf16tof(w.y & 0xFFFFu);
        s3 += bf16tof(w.y >> 16);
    }
    const f32x4 u = Uv[x];
    out[x] = (f32x4){s0 - u[0], s1 - u[1], s2 - u[2], s3 - u[3]};
}

extern "C" void kernel_launch(void* const* d_in, const int* in_sizes, int n_in,
                              void* d_out, int out_size, void* d_ws, size_t ws_size,
                              hipStream_t stream) {
    const float* U   = (const float*)d_in[0];
    const float* ref = (const float*)d_in[1];
    float* out = (float*)d_out;

    // ws: utPack 2 MB | packA 1 MB | packB 1 MB | bf16 partials 32 MB (JS=16)
    unsigned short* utPack = (unsigned short*)d_ws;
    unsigned short* packA  = (unsigned short*)((char*)d_ws + (size_t)2 * 1024 * 1024);
    unsigned short* packB  = (unsigned short*)((char*)d_ws + (size_t)3 * 1024 * 1024);
    unsigned short* part   = (unsigned short*)((char*)d_ws + (size_t)4 * 1024 * 1024);

    const size_t MB = 1024 * 1024;
    prep_all<<<768, 256, 0, stream>>>(U, ref, packA, packB, utPack);

    if (ws_size >= 36 * MB) {
        lsh_main<16><<<IBLOCKS * 16, 256, 0, stream>>>(U, packA, packB, utPack,
                                                       part, out, 1);
        reduce_part<16><<<1024, 256, 0, stream>>>(part, (const f32x4*)U, (f32x4*)out);
    } else {
        hipMemsetAsync(d_out, 0, (size_t)out_size * sizeof(float), stream);
        lsh_main<8><<<IBLOCKS * 8, 256, 0, stream>>>(U, packA, packB, utPack,
                                                     part, out, 0);
    }
}

// Round 12
// 122.839 us; speedup vs baseline: 4.4426x; 1.1163x over previous
//
#include <hip/hip_runtime.h>
#include <hip/hip_bf16.h>
#include <stdint.h>

#define N_PTS 16384
#define C_CH  64
#define D_REF 5
#define LOG2E 1.44269504088896340736f
#define IBLOCKS 64        // 256 i per block (4 waves x 4 i-tiles x 16)

typedef __attribute__((ext_vector_type(8))) short bf16x8;
typedef __attribute__((ext_vector_type(4))) float f32x4;

__device__ __forceinline__ unsigned short bf16rn(float v) {
    unsigned u = __builtin_bit_cast(unsigned, v) + 0x8000u;   // round-half-up
    return (unsigned short)(u >> 16);
}
__device__ __forceinline__ float bf16tof(unsigned x) {
    return __builtin_bit_cast(float, x << 16);
}
__device__ __forceinline__ unsigned pack2bf16(float lo, float hi) {
    unsigned a = __builtin_bit_cast(unsigned, lo) + 0x8000u;
    unsigned b = __builtin_bit_cast(unsigned, hi) + 0x8000u;
    return __builtin_amdgcn_perm(b, a, 0x07060302u);
}
__device__ __forceinline__ unsigned cvt2(float lo, float hi) {
#if __has_builtin(__builtin_amdgcn_cvt_pk_bf16_f32)
    typedef __attribute__((ext_vector_type(2))) __bf16 bf162_t;
    bf162_t r = __builtin_amdgcn_cvt_pk_bf16_f32(lo, hi);
    return __builtin_bit_cast(unsigned, r);
#else
    return pack2bf16(lo, hi);
#endif
}
__device__ __forceinline__ float fast_exp2(float x) {
#if __has_builtin(__builtin_amdgcn_exp2f)
    return __builtin_amdgcn_exp2f(x);
#else
    return exp2f(x);
#endif
}
__device__ __forceinline__ void dma16(const unsigned short* g, unsigned short* l) {
#if __has_builtin(__builtin_amdgcn_global_load_lds)
    __builtin_amdgcn_global_load_lds(
        (const __attribute__((address_space(1))) unsigned int*)g,
        (__attribute__((address_space(3))) unsigned int*)l, 16, 0, 0);
#else
    const int lane = threadIdx.x & 63;
    *(uint4*)(l + lane * 8) = *(const uint4*)(g);
#endif
}

// ---------------------------------------------------------------------------
// prep (verified R5-R11, absmax 0.5): G = log2e*(ri.rj) + hi + hj via hi/lo
// bf16 splits; PV-DIRECT PERMUTATION bakes the j-order into packA rows so the
// G-pair output regs on lane (q,m) ARE the PV B-fragment.
__global__ __launch_bounds__(256) void prep_all(
    const float* __restrict__ U, const float* __restrict__ ref,
    unsigned short* __restrict__ packA, unsigned short* __restrict__ packB,
    unsigned short* __restrict__ utPack)
{
    __shared__ unsigned short tile[64 * 80];
    const int bid = blockIdx.x;
    const int t   = threadIdx.x;

    if (bid < 512) {
        const int gid  = bid * 256 + t;                // 131072 total
        const int half = gid >> 16;                    // 0 = A(j), 1 = B(i)
        const int id   = gid & 0xFFFF;
        const int tile16 = id >> 6;
        const int lane = id & 63;
        const int q    = lane >> 4;
        const int m    = lane & 15;
        const int p = half ? (tile16 * 16 + m)
                           : ((tile16 >> 1) * 32 + (m >> 2) * 8 + (m & 3) + (tile16 & 1) * 4);

        const float* r = ref + (size_t)p * D_REF;
        float rv[5];
        float sq = 0.f;
#pragma unroll
        for (int d = 0; d < 5; ++d) { rv[d] = r[d]; sq += rv[d] * rv[d]; }
        const float h = -0.5f * LOG2E * sq;

        unsigned short bh[5], bl[5];
#pragma unroll
        for (int d = 0; d < 5; ++d) {
            const float base = half ? rv[d] * LOG2E : rv[d];
            bh[d] = bf16rn(base);
            bl[d] = bf16rn(base - bf16tof((unsigned)bh[d]));
        }
        const unsigned short hh  = bf16rn(h);
        const unsigned short hl  = bf16rn(h - bf16tof((unsigned)hh));
        const unsigned short one = 0x3F80;

        unsigned short outv[8];
#pragma unroll
        for (int tt = 0; tt < 8; ++tt) {
            const int k = q * 8 + tt;
            unsigned short v = 0;
            if (!half) {
                if      (k < 5)   v = bh[k];
                else if (k < 10)  v = bh[k - 5];
                else if (k < 15)  v = bl[k - 10];
                else if (k == 15) v = hh;
                else if (k == 16) v = hl;
                else if (k <= 18) v = one;
            } else {
                if      (k < 5)   v = bh[k];
                else if (k < 10)  v = bl[k - 5];
                else if (k < 15)  v = bh[k - 10];
                else if (k <= 16) v = one;
                else if (k == 17) v = hh;
                else if (k == 18) v = hl;
            }
            outv[tt] = v;
        }
        unsigned short* dst = (half ? packB : packA) + ((size_t)tile16 * 64 + lane) * 8;
        *(uint4*)dst = *(uint4*)outv;
    } else {
        const int b  = bid - 512;
        const int j0 = b * 64;
        const int c  = t & 63;
        const int jb = t >> 6;
#pragma unroll
        for (int k = 0; k < 16; ++k) {
            const int jr = jb + k * 4;
            tile[c * 80 + jr] = bf16rn(U[(size_t)(j0 + jr) * C_CH + c]);  // coalesced by c
        }
        __syncthreads();
#pragma unroll
        for (int rep = 0; rep < 2; ++rep) {
            const int id   = rep * 256 + t;            // 512 frag-lanes
            const int lane = id & 63;
            const int ct   = (id >> 6) & 3;
            const int kt   = id >> 8;                  // 0..1
            const int m    = lane & 15;
            const int q    = lane >> 4;
            const uint4 frag = *(const uint4*)&tile[(ct * 16 + m) * 80 + kt * 32 + q * 8];
            const int jtile  = b * 2 + kt;
            *(uint4*)&utPack[(((size_t)jtile * 4 + ct) * 64 + lane) * 8] = frag;
        }
    }
}

// ---------------------------------------------------------------------------
// main == R5's proven 62.2us K-loop (single-buffer staging of BOTH utPack and
// packA, 24 KB / 128-j chunk, 2 barriers/chunk, s=4 grouped inner, VGPR~60 ->
// 4-blocks/CU capable). Only change vs R5: bf16 lane-linear partial epilogue
// (R8-proven) halves partial write traffic 64->32 MB.
// LDS (shorts): [0,8192) utPack stage | [8192,12288) packA stage. 24 KB.
template<int JS>
__global__ __launch_bounds__(256, 4) void lsh_main(
    const float* __restrict__ U,
    const unsigned short* __restrict__ packA,
    const unsigned short* __restrict__ packB,
    const unsigned short* __restrict__ utPack,
    unsigned short* __restrict__ part,
    float* __restrict__ out,
    int use_part)
{
    constexpr int CHUNKS = (N_PTS / JS) / 128;
    __shared__ __align__(16) unsigned short sh[12288];   // 24 KB

    const int t    = threadIdx.x;
    const int lane = t & 63;
    const int wave = t >> 6;
    const int q    = lane >> 4;
    const int m    = lane & 15;

    const int ib = blockIdx.x / JS;
    const int js = blockIdx.x % JS;

    bf16x8 bfrag[4];
#pragma unroll
    for (int s = 0; s < 4; ++s) {
        const int itile = ib * 16 + wave * 4 + s;
        bfrag[s] = *(const bf16x8*)(packB + ((size_t)itile * 64 + lane) * 8);
    }

    f32x4 acc[4][4];
#pragma unroll
    for (int s = 0; s < 4; ++s)
#pragma unroll
        for (int ct = 0; ct < 4; ++ct) acc[s][ct] = (f32x4){0.f, 0.f, 0.f, 0.f};

    for (int chunk = 0; chunk < CHUNKS; ++chunk) {
        const unsigned short* srcU = utPack + (size_t)(js * CHUNKS + chunk) * 8192;
        const unsigned short* srcA = packA  + (size_t)(js * CHUNKS + chunk) * 4096;
        __syncthreads();                               // prior chunk's reads done
#pragma unroll
        for (int r = 0; r < 4; ++r)
            dma16(srcU + r * 2048 + wave * 512 + lane * 8, sh + r * 2048 + wave * 512);
#pragma unroll
        for (int r = 0; r < 2; ++r)
            dma16(srcA + r * 2048 + wave * 512 + lane * 8, sh + 8192 + r * 2048 + wave * 512);
        __syncthreads();                               // drains vmcnt -> LDS valid

#pragma unroll
        for (int kt = 0; kt < 4; ++kt) {
            const bf16x8 ga0 = *(const bf16x8*)(sh + 8192 + (kt * 2 + 0) * 512 + lane * 8);
            const bf16x8 ga1 = *(const bf16x8*)(sh + 8192 + (kt * 2 + 1) * 512 + lane * 8);

            const f32x4 z = (f32x4){0.f, 0.f, 0.f, 0.f};
            bf16x8 sfrag[4];
#pragma unroll
            for (int s = 0; s < 4; ++s) {
                const f32x4 g0 = __builtin_amdgcn_mfma_f32_16x16x32_bf16(ga0, bfrag[s], z, 0, 0, 0);
                const f32x4 g1 = __builtin_amdgcn_mfma_f32_16x16x32_bf16(ga1, bfrag[s], z, 0, 0, 0);
                union { unsigned u[4]; bf16x8 v; } sb;
                sb.u[0] = cvt2(fast_exp2(g0[0]), fast_exp2(g0[1]));
                sb.u[1] = cvt2(fast_exp2(g0[2]), fast_exp2(g0[3]));
                sb.u[2] = cvt2(fast_exp2(g1[0]), fast_exp2(g1[1]));
                sb.u[3] = cvt2(fast_exp2(g1[2]), fast_exp2(g1[3]));
                sfrag[s] = sb.v;                       // == PV B-frag for 32 j
            }
#pragma unroll
            for (int ct = 0; ct < 4; ++ct) {
                const bf16x8 uf = *(const bf16x8*)(sh + kt * 2048 + ct * 512 + lane * 8);
#pragma unroll
                for (int s = 0; s < 4; ++s)
                    acc[s][ct] = __builtin_amdgcn_mfma_f32_16x16x32_bf16(
                        uf, sfrag[s], acc[s][ct], 0, 0, 0);
            }
        }
    }

    if (use_part) {
        // bf16 partials, lane-linear 16 B/lane (fully coalesced, no RMW):
        // short index = blk*16384 + ((s*2+cp)*256 + t)*8 + cti*4 + r2
        unsigned short* dst = part + ((size_t)js * IBLOCKS + ib) * 16384;
#pragma unroll
        for (int s = 0; s < 4; ++s)
#pragma unroll
            for (int cp = 0; cp < 2; ++cp) {
                uint4 w;
                w.x = cvt2(acc[s][cp*2+0][0], acc[s][cp*2+0][1]);
                w.y = cvt2(acc[s][cp*2+0][2], acc[s][cp*2+0][3]);
                w.z = cvt2(acc[s][cp*2+1][0], acc[s][cp*2+1][1]);
                w.w = cvt2(acc[s][cp*2+1][2], acc[s][cp*2+1][3]);
                *(uint4*)(dst + ((s * 2 + cp) * 256 + t) * 8) = w;
            }
    } else {
#pragma unroll
        for (int s = 0; s < 4; ++s) {
            const int i_glob = ib * 256 + (wave * 4 + s) * 16 + m;
#pragma unroll
            for (int ct = 0; ct < 4; ++ct)
#pragma unroll
                for (int r2 = 0; r2 < 4; ++r2) {
                    const int c = ct * 16 + q * 4 + r2;
                    float val = acc[s][ct][r2];
                    if (js == 0) val -= U[(size_t)i_glob * C_CH + c];
                    atomicAdd(&out[(size_t)i_glob * C_CH + c], val);
                }
        }
    }
}

// ---------------------------------------------------------------------------
// reduce (R8-proven): out = sum_js bf16(part[js]) - U, gather-decoding the
// lane-linear partial layout; output writes are coalesced f32x4.
template<int JS>
__global__ __launch_bounds__(256) void reduce_part(
    const unsigned short* __restrict__ part, const f32x4* __restrict__ Uv,
    f32x4* __restrict__ out)
{
    const int x  = blockIdx.x * 256 + threadIdx.x;     // [0, 2^18) f32x4 units
    const int i  = x >> 4;
    const int c4 = (x & 15) * 4;                        // c = c4 .. c4+3
    const int blk = i >> 8, il = i & 255;
    const int wv = il >> 6, s = (il >> 4) & 3, mm = il & 15;
    const int ct = c4 >> 4, qq = (c4 >> 2) & 3;
    const int cp = ct >> 1, cti = ct & 1;
    const size_t off = (size_t)blk * 16384 +
        (size_t)(((s * 2 + cp) * 256) + (wv * 64 + qq * 16 + mm)) * 8 + cti * 4;
    float s0 = 0.f, s1 = 0.f, s2 = 0.f, s3 = 0.f;
#pragma unroll
    for (int js = 0; js < JS; ++js) {
        const uint2 w = *(const uint2*)(part + (size_t)js * (IBLOCKS * 16384) + off);
        s0 += bf16tof(w.x & 0xFFFFu);
        s1 += bf16tof(w.x >> 16);
        s2 += bf16tof(w.y & 0xFFFFu);
        s3 += bf16tof(w.y >> 16);
    }
    const f32x4 u = Uv[x];
    out[x] = (f32x4){s0 - u[0], s1 - u[1], s2 - u[2], s3 - u[3]};
}

extern "C" void kernel_launch(void* const* d_in, const int* in_sizes, int n_in,
                              void* d_out, int out_size, void* d_ws, size_t ws_size,
                              hipStream_t stream) {
    const float* U   = (const float*)d_in[0];
    const float* ref = (const float*)d_in[1];
    float* out = (float*)d_out;

    // ws: utPack 2 MB | packA 1 MB | packB 1 MB | bf16 partials 32 MB (JS=16)
    unsigned short* utPack = (unsigned short*)d_ws;
    unsigned short* packA  = (unsigned short*)((char*)d_ws + (size_t)2 * 1024 * 1024);
    unsigned short* packB  = (unsigned short*)((char*)d_ws + (size_t)3 * 1024 * 1024);
    unsigned short* part   = (unsigned short*)((char*)d_ws + (size_t)4 * 1024 * 1024);

    const size_t MB = 1024 * 1024;
    prep_all<<<768, 256, 0, stream>>>(U, ref, packA, packB, utPack);

    if (ws_size >= 36 * MB) {
        lsh_main<16><<<IBLOCKS * 16, 256, 0, stream>>>(U, packA, packB, utPack,
                                                       part, out, 1);
        reduce_part<16><<<1024, 256, 0, stream>>>(part, (const f32x4*)U, (f32x4*)out);
    } else {
        hipMemsetAsync(d_out, 0, (size_t)out_size * sizeof(float), stream);
        lsh_main<8><<<IBLOCKS * 8, 256, 0, stream>>>(U, packA, packB, utPack,
                                                     part, out, 0);
    }
}